// Round 4
// baseline (999.083 us; speedup 1.0000x reference)
//
#include <hip/hip_runtime.h>
#include <math.h>

static constexpr int cB  = 8;
static constexpr int cN  = 4096;
static constexpr int cD  = 256;
static constexpr int cBN = cB * cN;
#define PI_F 3.14159265358979323846f

__device__ __forceinline__ float2 cmul(float2 a, float2 b) {
    return make_float2(a.x*b.x - a.y*b.y, a.x*b.y + a.y*b.x);
}
__device__ __forceinline__ float2 cfma2(float2 a, float2 b, float2 acc) {
    acc.x += a.x*b.x - a.y*b.y;
    acc.y += a.x*b.y + a.y*b.x;
    return acc;
}
__device__ __forceinline__ float2 cneg(float2 a) { return make_float2(-a.x, -a.y); }

struct G4 { float2 ii, ij, ji, jj; };

__device__ __forceinline__ G4 givens_f(float al, float be, float ga) {
    float ra = (al + be) * (PI_F * 0.5f);
    float rs = (al - be) * (PI_F * 0.5f);
    float gm = ga * (PI_F * 0.5f);
    float sg, cg, sra, cra, srs, crs;
    sincosf(gm, &sg, &cg);
    sincosf(ra, &sra, &cra);
    sincosf(rs, &srs, &crs);
    G4 g;
    g.ii = make_float2( cra*cg, -sra*cg);
    g.ij = make_float2( crs*sg, -srs*sg);
    g.ji = make_float2(-crs*sg, -srs*sg);
    g.jj = make_float2( cra*cg,  sra*cg);
    return g;
}

// Diagnostic sentinel writer
__global__ void sentinel_kernel(float* out, int n, float v) {
    if (n > 0) out[0] = v;
    if (n > 1) out[1] = v;
}

// ---------------------------------------------------------------------------
// Kernel 1: fused dual-SIREN + DIAG. Block = 32 rows x 256 cols, 256 threads.
// ---------------------------------------------------------------------------
__device__ __forceinline__ void gemm_tile(const float* src /*LDS [32][256]*/,
                                          const float* __restrict__ W /*[256][256]*/,
                                          const float* __restrict__ bias,
                                          int tr, int tc, float h[4][8]) {
    float acc[4][8];
    #pragma unroll
    for (int i = 0; i < 4; ++i)
        #pragma unroll
        for (int j = 0; j < 8; ++j) acc[i][j] = 0.f;
    #pragma unroll 2
    for (int k0 = 0; k0 < 256; k0 += 4) {
        float4 xv[4];
        float4 wv[8];
        #pragma unroll
        for (int i = 0; i < 4; ++i)
            xv[i] = *(const float4*)(src + (4*tr+i)*256 + k0);
        #pragma unroll
        for (int j = 0; j < 8; ++j)
            wv[j] = *(const float4*)(W + (tc*8+j)*256 + k0);
        #pragma unroll
        for (int i = 0; i < 4; ++i)
            #pragma unroll
            for (int j = 0; j < 8; ++j)
                acc[i][j] += xv[i].x*wv[j].x + xv[i].y*wv[j].y
                           + xv[i].z*wv[j].z + xv[i].w*wv[j].w;
    }
    #pragma unroll
    for (int j = 0; j < 8; ++j) {
        float bj = bias[tc*8+j];
        #pragma unroll
        for (int i = 0; i < 4; ++i) h[i][j] = acc[i][j] + bj;
    }
}

__device__ __forceinline__ void stage_x(const float* __restrict__ x, size_t r0,
                                        float* buf, int tid) {
    const float4* xg = (const float4*)(x + r0*256);
    float4* b4 = (float4*)buf;
    #pragma unroll
    for (int i = 0; i < 8; ++i) b4[tid + i*256] = xg[tid + i*256];
}

__device__ __forceinline__ void act_store(float* buf, int tr, int tc, const float h[4][8]) {
    #pragma unroll
    for (int i = 0; i < 4; ++i) {
        *(float4*)(buf + (4*tr+i)*256 + tc*8)     = make_float4(h[i][0], h[i][1], h[i][2], h[i][3]);
        *(float4*)(buf + (4*tr+i)*256 + tc*8 + 4) = make_float4(h[i][4], h[i][5], h[i][6], h[i][7]);
    }
}

__device__ __forceinline__ void scale_norm_h(float h[4][8], float g) {
    float rn[4];
    #pragma unroll
    for (int i = 0; i < 4; ++i) {
        float s = 0.f;
        #pragma unroll
        for (int j = 0; j < 8; ++j) s += h[i][j]*h[i][j];
        rn[i] = s;
    }
    #pragma unroll
    for (int mk = 1; mk < 32; mk <<= 1)
        #pragma unroll
        for (int i = 0; i < 4; ++i) rn[i] += __shfl_xor(rn[i], mk);
    #pragma unroll
    for (int i = 0; i < 4; ++i) {
        float sc = g / fmaxf(sqrtf(rn[i]), 1e-5f);
        #pragma unroll
        for (int j = 0; j < 8; ++j) h[i][j] *= sc;
    }
}

__global__ __launch_bounds__(256) void siren_kernel(
    const float* __restrict__ x,
    const float* __restrict__ ev_w1, const float* __restrict__ ev_b1, const float* __restrict__ ev_g,
    const float* __restrict__ ev_w2, const float* __restrict__ ev_b2,
    const float* __restrict__ hp_w1, const float* __restrict__ hp_b1, const float* __restrict__ hp_g,
    const float* __restrict__ hp_w2, const float* __restrict__ hp_b2,
    const float* __restrict__ cheb,
    float* __restrict__ Pout, float2* __restrict__ DIAG)
{
    __shared__ float buf[32*256];
    const int tid = threadIdx.x;
    const int tr = tid >> 5;
    const int tc = tid & 31;
    const size_t r0 = (size_t)blockIdx.x * 32;
    const int b = (int)(r0 >> 12);

    float h[4][8];

    // ===================== EV network =====================
    stage_x(x, r0, buf, tid);
    __syncthreads();
    gemm_tile(buf, ev_w1, ev_b1, tr, tc, h);
    #pragma unroll
    for (int i = 0; i < 4; ++i)
        #pragma unroll
        for (int j = 0; j < 8; ++j) h[i][j] = sinf(h[i][j]);
    scale_norm_h(h, ev_g[0]);
    __syncthreads();
    act_store(buf, tr, tc, h);
    __syncthreads();
    gemm_tile(buf, ev_w2, ev_b2, tr, tc, h);
    {   // eig = mean over 256 features of sin(.); then DIAG
        float es[4];
        #pragma unroll
        for (int i = 0; i < 4; ++i) {
            float s = 0.f;
            #pragma unroll
            for (int j = 0; j < 8; ++j) s += sinf(h[i][j]);
            es[i] = s;
        }
        #pragma unroll
        for (int mk = 1; mk < 32; mk <<= 1)
            #pragma unroll
            for (int i = 0; i < 4; ++i) es[i] += __shfl_xor(es[i], mk);
        if (tc == 0) {
            float dmp[9];
            {
                const double c = 3.14159265358979323846 / 10.0;
                double sc = sin(c), cc = cos(c);
                dmp[0] = 1.f;
                for (int k = 1; k < 9; ++k)
                    dmp[k] = (float)(((10.0 - k) * sc * cos(k*c) + cc * sin(k*c)) / (10.0 * sc));
            }
            const float* cf = cheb + b*9;
            #pragma unroll
            for (int i = 0; i < 4; ++i) {
                float ev = es[i] * (1.f/256.f);
                float t0 = 1.f, t1 = ev;
                float filt = cf[0] + ev * cf[1] * dmp[1];
                #pragma unroll
                for (int k = 2; k < 9; ++k) {
                    float t2 = 2.f*ev*t1 - t0;
                    filt += t2 * cf[k] * dmp[k];
                    t0 = t1; t1 = t2;
                }
                float sp, cp;
                sincosf(PI_F * ev, &sp, &cp);   // exp(2i*pi*Q*eig), Q=0.5
                DIAG[r0 + 4*tr + i] = make_float2(filt*cp, filt*sp);
            }
        }
    }
    __syncthreads();

    // ===================== HP network =====================
    stage_x(x, r0, buf, tid);
    __syncthreads();
    gemm_tile(buf, hp_w1, hp_b1, tr, tc, h);
    #pragma unroll
    for (int i = 0; i < 4; ++i)
        #pragma unroll
        for (int j = 0; j < 8; ++j) h[i][j] = sinf(h[i][j]);
    scale_norm_h(h, hp_g[0]);
    __syncthreads();
    act_store(buf, tr, tc, h);
    __syncthreads();
    gemm_tile(buf, hp_w2, hp_b2, tr, tc, h);
    #pragma unroll
    for (int i = 0; i < 4; ++i)
        #pragma unroll
        for (int j = 0; j < 8; ++j) h[i][j] = sinf(h[i][j]);
    {   // AdaptiveAvgPool1d(6) over 256 features (torch bins), flat [B][6N] store
        const int sb[6]  = {0, 42, 85, 128, 170, 213};
        const int ebd[6] = {43, 86, 128, 171, 214, 256};
        float part[4][6];
        #pragma unroll
        for (int i = 0; i < 4; ++i)
            #pragma unroll
            for (int q = 0; q < 6; ++q) part[i][q] = 0.f;
        #pragma unroll
        for (int j = 0; j < 8; ++j) {
            int e = tc*8 + j;
            #pragma unroll
            for (int q = 0; q < 6; ++q) {
                if (e >= sb[q] && e < ebd[q]) {
                    #pragma unroll
                    for (int i = 0; i < 4; ++i) part[i][q] += h[i][j];
                }
            }
        }
        #pragma unroll
        for (int mk = 1; mk < 32; mk <<= 1)
            #pragma unroll
            for (int q = 0; q < 6; ++q)
                #pragma unroll
                for (int i = 0; i < 4; ++i) part[i][q] += __shfl_xor(part[i][q], mk);
        if (tc == 0) {
            const float cnt[6] = {43.f, 44.f, 43.f, 43.f, 44.f, 43.f};
            #pragma unroll
            for (int i = 0; i < 4; ++i) {
                size_t row = r0 + 4*tr + i;
                int nn = (int)(row & 4095);
                #pragma unroll
                for (int q = 0; q < 6; ++q)
                    Pout[(size_t)b*6*cN + nn*6 + q] = part[i][q] / cnt[q];
            }
        }
    }
}

// ---------------------------------------------------------------------------
// Kernel 2: both DHHP transforms fused; Givens recomputed per block from P.
// Tile: 32 n-rows (halo 4) x 64 d. mode 0: store real part only (float out);
// mode 1: interleaved complex (float2 out). All stores bounded by out_floats.
// ---------------------------------------------------------------------------
__global__ __launch_bounds__(256) void dhhp_kernel(
    const float* __restrict__ x, const float* __restrict__ P,
    const float2* __restrict__ DIAG, float* __restrict__ outf,
    unsigned long long out_floats, int mode)
{
    __shared__ float  xsr[40*64];
    __shared__ float2 bufA[38*64];
    __shared__ float2 bufB[36*64];
    __shared__ float2 cA[38], cBv[38], cC[38], cDg[36];
    __shared__ G4 uG[39], lG[39];

    const int tid = threadIdx.x;
    const int n0 = blockIdx.x * 32;
    const int d0 = blockIdx.y * 64;
    const int b  = blockIdx.z;
    const size_t bbase = (size_t)b * cN;
    const int b6 = b * 6 * cN;
    const float2 z2 = make_float2(0.f, 0.f);

    for (int idx = tid; idx < 40*64; idx += 256) {
        int r = idx >> 6, d = idx & 63;
        int m = n0 - 4 + r;
        float v = 0.f;
        if (m >= 0 && m < cN) v = x[(bbase + m)*cD + d0 + d];
        xsr[idx] = v;
    }
    if (tid < 78) {
        int t = (tid < 39) ? tid : tid - 39;
        int j = n0 - 4 + t;
        G4 g; g.ii = g.ij = g.ji = g.jj = z2;
        if (j >= 0 && j <= cN-2) {
            if (tid < 39) g = givens_f(P[b6+3*cN+j], P[b6+4*cN+j], P[b6+5*cN+j]);   // u[j]
            else          g = givens_f(P[b6+j+1],    P[b6+cN+j+1], P[b6+2*cN+j+1]); // l[j]
        }
        if (tid < 39) uG[t] = g; else lG[t] = g;
    }
    __syncthreads();

    // ---- stage 1: Y = U x ----
    if (tid < 38) {
        int m = n0 - 3 + tid;
        float2 A=z2, Bv=z2, C=z2;
        if (m >= 0 && m < cN) {
            if (m == 0)         { Bv = uG[tid+1].ii; C = uG[tid+1].ij; }
            else if (m == cN-1) { A = uG[tid].ji; Bv = uG[tid].jj; }
            else { A = uG[tid].ji; Bv = cmul(uG[tid].jj, uG[tid+1].ii); C = cmul(uG[tid].jj, uG[tid+1].ij); }
        }
        cA[tid]=A; cBv[tid]=Bv; cC[tid]=C;
    }
    __syncthreads();
    for (int idx = tid; idx < 38*64; idx += 256) {
        int r = idx >> 6;
        float x0 = xsr[idx], x1 = xsr[idx+64], x2 = xsr[idx+128];
        float2 A = cA[r], Bv = cBv[r], C = cC[r];
        bufA[idx] = make_float2(A.x*x0 + Bv.x*x1 + C.x*x2,
                                A.y*x0 + Bv.y*x1 + C.y*x2);
    }
    __syncthreads();

    // ---- stage 2: Z = diag .* (L Y) ----
    if (tid < 36) {
        int m = n0 - 2 + tid;
        float2 A=z2, Bv=z2, C=z2, Dg=z2;
        if (m >= 0 && m < cN) {
            Dg = DIAG[bbase + m];
            if (m == 0)         { Bv = lG[tid+2].ii; C = lG[tid+2].ij; }
            else if (m == cN-1) { A = lG[tid+1].ji; Bv = lG[tid+1].jj; }
            else { A = cmul(lG[tid+2].ii, lG[tid+1].ji); Bv = cmul(lG[tid+2].ii, lG[tid+1].jj); C = lG[tid+2].ij; }
        }
        cA[tid]=A; cBv[tid]=Bv; cC[tid]=C; cDg[tid]=Dg;
    }
    __syncthreads();
    for (int idx = tid; idx < 36*64; idx += 256) {
        int r = idx >> 6;
        float2 y0 = bufA[idx], y1 = bufA[idx+64], y2 = bufA[idx+128];
        float2 zv = cmul(cA[r], y0);
        zv = cfma2(cBv[r], y1, zv);
        zv = cfma2(cC[r], y2, zv);
        bufB[idx] = cmul(cDg[r], zv);
    }
    __syncthreads();

    // ---- stage 3: W = U' Z (conj-transpose u) ----
    if (tid < 34) {
        int m = n0 - 1 + tid;
        float2 A=z2, Bv=z2, C=z2;
        if (m >= 0 && m < cN) {
            if (m == 0)         { Bv = uG[tid+3].jj; C = cneg(uG[tid+3].ij); }
            else if (m == cN-1) { A = cneg(uG[tid+2].ji); Bv = uG[tid+2].ii; }
            else { A = cneg(uG[tid+2].ji); Bv = cmul(uG[tid+2].ii, uG[tid+3].jj); C = cneg(cmul(uG[tid+2].ii, uG[tid+3].ij)); }
        }
        cA[tid]=A; cBv[tid]=Bv; cC[tid]=C;
    }
    __syncthreads();
    for (int idx = tid; idx < 34*64; idx += 256) {
        int r = idx >> 6;
        float2 zv0 = bufB[idx], zv1 = bufB[idx+64], zv2 = bufB[idx+128];
        float2 w = cmul(cA[r], zv0);
        w = cfma2(cBv[r], zv1, w);
        w = cfma2(cC[r], zv2, w);
        bufA[idx] = w;
    }
    __syncthreads();

    // ---- stage 4: out = L' W ----
    if (tid < 32) {
        int m = n0 + tid;
        float2 A=z2, Bv=z2, C=z2;
        if (m == 0)         { Bv = lG[tid+4].jj; C = cneg(lG[tid+4].ij); }
        else if (m == cN-1) { A = cneg(lG[tid+3].ji); Bv = lG[tid+3].ii; }
        else { A = cneg(cmul(lG[tid+4].jj, lG[tid+3].ji)); Bv = cmul(lG[tid+4].jj, lG[tid+3].ii); C = cneg(lG[tid+4].ij); }
        cA[tid]=A; cBv[tid]=Bv; cC[tid]=C;
    }
    __syncthreads();
    for (int idx = tid; idx < 32*64; idx += 256) {
        int r = idx >> 6, d = idx & 63;
        float2 w0 = bufA[idx], w1 = bufA[idx+64], w2 = bufA[idx+128];
        float2 o = cmul(cA[r], w0);
        o = cfma2(cBv[r], w1, o);
        o = cfma2(cC[r], w2, o);
        unsigned long long ci = (unsigned long long)((bbase + n0 + r)*(size_t)cD + d0 + d);
        if (mode == 0) {
            // real part only: d_out is float[B*N*D]
            if (ci < out_floats) outf[ci] = o.x;
        } else {
            // interleaved complex: d_out is float[2*B*N*D]
            if (2ULL*ci + 2ULL <= out_floats) ((float2*)outf)[ci] = o;
        }
    }
}

// ---------------------------------------------------------------------------
extern "C" void kernel_launch(void* const* d_in, const int* in_sizes, int n_in,
                              void* d_out, int out_size, void* d_ws, size_t ws_size,
                              hipStream_t stream)
{
    // ---- verify the input map before touching anything ----
    const int expect[12] = { cBN*cD, cD*cD, cD, 1, cD*cD, cD,
                             cD*cD, cD, 1, cD*cD, cD, cB*9 };
    bool ok = (n_in == 12);
    if (ok) for (int i = 0; i < 12; ++i) ok = ok && (in_sizes[i] == expect[i]);
    if (!ok) {
        sentinel_kernel<<<1, 1, 0, stream>>>((float*)d_out, out_size, 1.0e6f);
        return;
    }
    const size_t pBytes = (size_t)cB * 6 * cN * sizeof(float);   // 768 KB
    const size_t dBytes = (size_t)cBN * sizeof(float2);          // 256 KB
    if (d_ws == nullptr || ws_size < pBytes + dBytes) {
        sentinel_kernel<<<1, 1, 0, stream>>>((float*)d_out, out_size, 2.0e6f);
        return;
    }
    // out_size semantics: evidence (out_npz ~32MB raw) says the harness holds
    // the reference output as float32 real part, out_size == B*N*D. Also
    // support the interleaved-complex case out_size == 2*B*N*D.
    int mode;
    if (out_size == cBN * cD)          mode = 0;
    else if (out_size == 2 * cBN * cD) mode = 1;
    else {
        sentinel_kernel<<<1, 1, 0, stream>>>((float*)d_out, out_size, 3.0e6f);
        return;
    }

    const float* x     = (const float*)d_in[0];
    const float* ev_w1 = (const float*)d_in[1];
    const float* ev_b1 = (const float*)d_in[2];
    const float* ev_g  = (const float*)d_in[3];
    const float* ev_w2 = (const float*)d_in[4];
    const float* ev_b2 = (const float*)d_in[5];
    const float* hp_w1 = (const float*)d_in[6];
    const float* hp_b1 = (const float*)d_in[7];
    const float* hp_g  = (const float*)d_in[8];
    const float* hp_w2 = (const float*)d_in[9];
    const float* hp_b2 = (const float*)d_in[10];
    const float* cheb  = (const float*)d_in[11];

    float*  P    = (float*)d_ws;
    float2* DIAG = (float2*)((char*)d_ws + pBytes);

    siren_kernel<<<dim3(cBN/32), 256, 0, stream>>>(x, ev_w1, ev_b1, ev_g, ev_w2, ev_b2,
                                                   hp_w1, hp_b1, hp_g, hp_w2, hp_b2,
                                                   cheb, P, DIAG);
    dhhp_kernel<<<dim3(cN/32, cD/64, cB), 256, 0, stream>>>(x, P, DIAG, (float*)d_out,
                                                            (unsigned long long)out_size,
                                                            mode);
}

// Round 5
// 240.213 us; speedup vs baseline: 4.1592x; 4.1592x over previous
//
#include <hip/hip_runtime.h>
#include <math.h>

typedef __attribute__((ext_vector_type(8))) _Float16 f16x8;
typedef __attribute__((ext_vector_type(4))) float    f32x4;

static constexpr int cB  = 8;
static constexpr int cN  = 4096;
static constexpr int cD  = 256;
static constexpr int cBN = cB * cN;
#define PI_F 3.14159265358979323846f

__device__ __forceinline__ float2 cmul(float2 a, float2 b) {
    return make_float2(a.x*b.x - a.y*b.y, a.x*b.y + a.y*b.x);
}
__device__ __forceinline__ float2 cfma2(float2 a, float2 b, float2 acc) {
    acc.x += a.x*b.x - a.y*b.y;
    acc.y += a.x*b.y + a.y*b.x;
    return acc;
}
__device__ __forceinline__ float2 cneg(float2 a) { return make_float2(-a.x, -a.y); }

struct G4 { float2 ii, ij, ji, jj; };

__device__ __forceinline__ G4 givens_f(float al, float be, float ga) {
    float ra = (al + be) * (PI_F * 0.5f);
    float rs = (al - be) * (PI_F * 0.5f);
    float gm = ga * (PI_F * 0.5f);
    float sg, cg, sra, cra, srs, crs;
    sincosf(gm, &sg, &cg);
    sincosf(ra, &sra, &cra);
    sincosf(rs, &srs, &crs);
    G4 g;
    g.ii = make_float2( cra*cg, -sra*cg);
    g.ij = make_float2( crs*sg, -srs*sg);
    g.ji = make_float2(-crs*sg, -srs*sg);
    g.jj = make_float2( cra*cg,  sra*cg);
    return g;
}

__global__ void sentinel_kernel(float* out, int n, float v) {
    if (n > 0) out[0] = v;
    if (n > 1) out[1] = v;
}

// ---------------------------------------------------------------------------
// Weight split: fp32 W -> f16 hi/lo pair. Layout: W16[2m] = hi, W16[2m+1] = lo,
// each [256*256] halves, m in {ev1, ev2, hp1, hp2}.
// ---------------------------------------------------------------------------
__global__ __launch_bounds__(256) void wcvt_kernel(
    const float* __restrict__ w0, const float* __restrict__ w1,
    const float* __restrict__ w2, const float* __restrict__ w3,
    _Float16* __restrict__ W16)
{
    int i = blockIdx.x * 256 + threadIdx.x;   // 0..65535
    const float* src[4] = {w0, w1, w2, w3};
    #pragma unroll
    for (int m = 0; m < 4; ++m) {
        float v = src[m][i];
        _Float16 hi = (_Float16)v;
        _Float16 lo = (_Float16)(v - (float)hi);
        W16[(size_t)(2*m)  *65536 + i] = hi;
        W16[(size_t)(2*m+1)*65536 + i] = lo;
    }
}

// ---------------------------------------------------------------------------
// SIREN via MFMA f16 hi/lo split. Block = 32 rows x 256 cols, 4 waves.
// Wave w owns cols [w*64, w*64+64) as 4 n-tiles; both 16-row m-tiles.
// LDS act arrays [32][256] f16, row stride 512B, XOR-swizzled byte^((row&7)<<4).
// ---------------------------------------------------------------------------
__device__ __forceinline__ void stage_x16(const float* __restrict__ xrow0,
                                          _Float16* aHi, _Float16* aLo, int tid)
{
    const int row = tid >> 3;          // 0..31
    const int c0  = (tid & 7) * 32;    // 32 cols per thread
    const float4* src = (const float4*)(xrow0 + row*256 + c0);
    const int swz = (row & 7) << 4;
    #pragma unroll
    for (int j = 0; j < 4; ++j) {
        float4 p = src[2*j], q = src[2*j+1];
        float v[8] = {p.x, p.y, p.z, p.w, q.x, q.y, q.z, q.w};
        f16x8 h, l;
        #pragma unroll
        for (int i = 0; i < 8; ++i) {
            _Float16 hi = (_Float16)v[i];
            h[i] = hi;
            l[i] = (_Float16)(v[i] - (float)hi);
        }
        int off = (((c0 + j*8) * 2) ^ swz);
        *(f16x8*)((char*)aHi + row*512 + off) = h;
        *(f16x8*)((char*)aLo + row*512 + off) = l;
    }
}

__device__ __forceinline__ void gemm16(const _Float16* aHi, const _Float16* aLo,
                                       const _Float16* __restrict__ wHi,
                                       const _Float16* __restrict__ wLo,
                                       int w, int lr, int kq, f32x4 acc[2][4])
{
    #pragma unroll
    for (int k0 = 0; k0 < 256; k0 += 32) {
        f16x8 ah[2], al[2];
        #pragma unroll
        for (int mt = 0; mt < 2; ++mt) {
            int row = mt*16 + lr;
            int off = (((k0 + kq*8) * 2) ^ ((row & 7) << 4));
            ah[mt] = *(const f16x8*)((const char*)aHi + row*512 + off);
            al[mt] = *(const f16x8*)((const char*)aLo + row*512 + off);
        }
        #pragma unroll
        for (int nt = 0; nt < 4; ++nt) {
            int col = w*64 + nt*16 + lr;
            f16x8 bh = *(const f16x8*)(wHi + col*256 + k0 + kq*8);
            f16x8 bl = *(const f16x8*)(wLo + col*256 + k0 + kq*8);
            #pragma unroll
            for (int mt = 0; mt < 2; ++mt) {
                acc[mt][nt] = __builtin_amdgcn_mfma_f32_16x16x32_f16(al[mt], bh, acc[mt][nt], 0, 0, 0);
                acc[mt][nt] = __builtin_amdgcn_mfma_f32_16x16x32_f16(ah[mt], bl, acc[mt][nt], 0, 0, 0);
                acc[mt][nt] = __builtin_amdgcn_mfma_f32_16x16x32_f16(ah[mt], bh, acc[mt][nt], 0, 0, 0);
            }
        }
    }
}

__global__ __launch_bounds__(256) void siren_mfma(
    const float* __restrict__ x, const _Float16* __restrict__ W16,
    const float* __restrict__ ev_b1, const float* __restrict__ ev_g,
    const float* __restrict__ ev_b2,
    const float* __restrict__ hp_b1, const float* __restrict__ hp_g,
    const float* __restrict__ hp_b2,
    const float* __restrict__ cheb,
    float* __restrict__ Pout, float2* __restrict__ DIAG)
{
    __shared__ _Float16 aHi[32*256];
    __shared__ _Float16 aLo[32*256];
    __shared__ float red[4][32];

    const int tid  = threadIdx.x;
    const int w    = tid >> 6;
    const int lane = tid & 63;
    const int lr   = lane & 15;
    const int kq   = lane >> 4;
    const size_t r0 = (size_t)blockIdx.x * 32;
    const int b = (int)(r0 >> 12);

    const _Float16* ev1h = W16 + 0*65536; const _Float16* ev1l = W16 + 1*65536;
    const _Float16* ev2h = W16 + 2*65536; const _Float16* ev2l = W16 + 3*65536;
    const _Float16* hp1h = W16 + 4*65536; const _Float16* hp1l = W16 + 5*65536;
    const _Float16* hp2h = W16 + 6*65536; const _Float16* hp2l = W16 + 7*65536;

    f32x4 acc[2][4];

    // ===================== EV layer 1 =====================
    stage_x16(x + r0*256, aHi, aLo, tid);
    __syncthreads();
    #pragma unroll
    for (int mt = 0; mt < 2; ++mt)
        #pragma unroll
        for (int nt = 0; nt < 4; ++nt) acc[mt][nt] = (f32x4)(0.f);
    gemm16(aHi, aLo, ev1h, ev1l, w, lr, kq, acc);
    {   // sin + ScaleNorm, then act -> LDS (hi/lo)
        float bv[4];
        #pragma unroll
        for (int nt = 0; nt < 4; ++nt) bv[nt] = ev_b1[w*64 + nt*16 + lr];
        float sv[2][4][4], rn[2][4];
        #pragma unroll
        for (int mt = 0; mt < 2; ++mt)
            #pragma unroll
            for (int r = 0; r < 4; ++r) {
                float s = 0.f;
                #pragma unroll
                for (int nt = 0; nt < 4; ++nt) {
                    float v = __sinf(acc[mt][nt][r] + bv[nt]);
                    sv[mt][nt][r] = v; s += v*v;
                }
                rn[mt][r] = s;
            }
        #pragma unroll
        for (int mk = 1; mk < 16; mk <<= 1)
            #pragma unroll
            for (int mt = 0; mt < 2; ++mt)
                #pragma unroll
                for (int r = 0; r < 4; ++r) rn[mt][r] += __shfl_xor(rn[mt][r], mk);
        if (lr == 0)
            #pragma unroll
            for (int mt = 0; mt < 2; ++mt)
                #pragma unroll
                for (int r = 0; r < 4; ++r) red[w][mt*16 + kq*4 + r] = rn[mt][r];
        __syncthreads();   // also: all GEMM1 reads of x done -> safe to overwrite act
        float g = ev_g[0];
        #pragma unroll
        for (int mt = 0; mt < 2; ++mt)
            #pragma unroll
            for (int r = 0; r < 4; ++r) {
                int row = mt*16 + kq*4 + r;
                float tot = red[0][row] + red[1][row] + red[2][row] + red[3][row];
                float sc = g / fmaxf(sqrtf(tot), 1e-5f);
                int swz = (row & 7) << 4;
                #pragma unroll
                for (int nt = 0; nt < 4; ++nt) {
                    float v = sv[mt][nt][r] * sc;
                    _Float16 hi = (_Float16)v;
                    _Float16 lo = (_Float16)(v - (float)hi);
                    int col = w*64 + nt*16 + lr;
                    int off = ((col*2) ^ swz);
                    *(_Float16*)((char*)aHi + row*512 + off) = hi;
                    *(_Float16*)((char*)aLo + row*512 + off) = lo;
                }
            }
    }
    __syncthreads();

    // ===================== EV layer 2 -> eig -> DIAG =====================
    #pragma unroll
    for (int mt = 0; mt < 2; ++mt)
        #pragma unroll
        for (int nt = 0; nt < 4; ++nt) acc[mt][nt] = (f32x4)(0.f);
    gemm16(aHi, aLo, ev2h, ev2l, w, lr, kq, acc);
    {
        float bv[4];
        #pragma unroll
        for (int nt = 0; nt < 4; ++nt) bv[nt] = ev_b2[w*64 + nt*16 + lr];
        float es[2][4];
        #pragma unroll
        for (int mt = 0; mt < 2; ++mt)
            #pragma unroll
            for (int r = 0; r < 4; ++r) {
                float s = 0.f;
                #pragma unroll
                for (int nt = 0; nt < 4; ++nt) s += sinf(acc[mt][nt][r] + bv[nt]); // precise: eig-critical
                es[mt][r] = s;
            }
        #pragma unroll
        for (int mk = 1; mk < 16; mk <<= 1)
            #pragma unroll
            for (int mt = 0; mt < 2; ++mt)
                #pragma unroll
                for (int r = 0; r < 4; ++r) es[mt][r] += __shfl_xor(es[mt][r], mk);
        if (lr == 0)
            #pragma unroll
            for (int mt = 0; mt < 2; ++mt)
                #pragma unroll
                for (int r = 0; r < 4; ++r) red[w][mt*16 + kq*4 + r] = es[mt][r];
        __syncthreads();
        if (tid < 32) {
            int row = tid;
            float ev = (red[0][row] + red[1][row] + red[2][row] + red[3][row]) * (1.f/256.f);
            float dmp[9];
            {
                const double c = 3.14159265358979323846 / 10.0;
                double sc = sin(c), cc = cos(c);
                dmp[0] = 1.f;
                for (int k = 1; k < 9; ++k)
                    dmp[k] = (float)(((10.0 - k) * sc * cos(k*c) + cc * sin(k*c)) / (10.0 * sc));
            }
            const float* cf = cheb + b*9;
            float t0 = 1.f, t1 = ev;
            float filt = cf[0] + ev * cf[1] * dmp[1];
            #pragma unroll
            for (int k = 2; k < 9; ++k) {
                float t2 = 2.f*ev*t1 - t0;
                filt += t2 * cf[k] * dmp[k];
                t0 = t1; t1 = t2;
            }
            float sp, cp;
            sincosf(PI_F * ev, &sp, &cp);
            DIAG[r0 + row] = make_float2(filt*cp, filt*sp);
        }
    }
    __syncthreads();   // GEMM2 reads done -> safe to restage x

    // ===================== HP layer 1 =====================
    stage_x16(x + r0*256, aHi, aLo, tid);
    __syncthreads();
    #pragma unroll
    for (int mt = 0; mt < 2; ++mt)
        #pragma unroll
        for (int nt = 0; nt < 4; ++nt) acc[mt][nt] = (f32x4)(0.f);
    gemm16(aHi, aLo, hp1h, hp1l, w, lr, kq, acc);
    {
        float bv[4];
        #pragma unroll
        for (int nt = 0; nt < 4; ++nt) bv[nt] = hp_b1[w*64 + nt*16 + lr];
        float sv[2][4][4], rn[2][4];
        #pragma unroll
        for (int mt = 0; mt < 2; ++mt)
            #pragma unroll
            for (int r = 0; r < 4; ++r) {
                float s = 0.f;
                #pragma unroll
                for (int nt = 0; nt < 4; ++nt) {
                    float v = __sinf(acc[mt][nt][r] + bv[nt]);
                    sv[mt][nt][r] = v; s += v*v;
                }
                rn[mt][r] = s;
            }
        #pragma unroll
        for (int mk = 1; mk < 16; mk <<= 1)
            #pragma unroll
            for (int mt = 0; mt < 2; ++mt)
                #pragma unroll
                for (int r = 0; r < 4; ++r) rn[mt][r] += __shfl_xor(rn[mt][r], mk);
        if (lr == 0)
            #pragma unroll
            for (int mt = 0; mt < 2; ++mt)
                #pragma unroll
                for (int r = 0; r < 4; ++r) red[w][mt*16 + kq*4 + r] = rn[mt][r];
        __syncthreads();
        float g = hp_g[0];
        #pragma unroll
        for (int mt = 0; mt < 2; ++mt)
            #pragma unroll
            for (int r = 0; r < 4; ++r) {
                int row = mt*16 + kq*4 + r;
                float tot = red[0][row] + red[1][row] + red[2][row] + red[3][row];
                float sc = g / fmaxf(sqrtf(tot), 1e-5f);
                int swz = (row & 7) << 4;
                #pragma unroll
                for (int nt = 0; nt < 4; ++nt) {
                    float v = sv[mt][nt][r] * sc;
                    _Float16 hi = (_Float16)v;
                    _Float16 lo = (_Float16)(v - (float)hi);
                    int col = w*64 + nt*16 + lr;
                    int off = ((col*2) ^ swz);
                    *(_Float16*)((char*)aHi + row*512 + off) = hi;
                    *(_Float16*)((char*)aLo + row*512 + off) = lo;
                }
            }
    }
    __syncthreads();

    // ===================== HP layer 2 -> pool -> Pout =====================
    #pragma unroll
    for (int mt = 0; mt < 2; ++mt)
        #pragma unroll
        for (int nt = 0; nt < 4; ++nt) acc[mt][nt] = (f32x4)(0.f);
    gemm16(aHi, aLo, hp2h, hp2l, w, lr, kq, acc);
    __syncthreads();   // all GEMM reads of act done before overwrite
    {
        float bv[4];
        #pragma unroll
        for (int nt = 0; nt < 4; ++nt) bv[nt] = hp_b2[w*64 + nt*16 + lr];
        #pragma unroll
        for (int mt = 0; mt < 2; ++mt)
            #pragma unroll
            for (int r = 0; r < 4; ++r) {
                int row = mt*16 + kq*4 + r;
                int swz = (row & 7) << 4;
                #pragma unroll
                for (int nt = 0; nt < 4; ++nt) {
                    float v = __sinf(acc[mt][nt][r] + bv[nt]);
                    int col = w*64 + nt*16 + lr;
                    int off = ((col*2) ^ swz);
                    *(_Float16*)((char*)aHi + row*512 + off) = (_Float16)v;
                }
            }
    }
    __syncthreads();
    if (tid < 192) {   // AdaptiveAvgPool1d(6), torch bins; flat [B][6N] store
        const int sb[6] = {0, 42, 85, 128, 170, 213};
        const int eb[6] = {43, 86, 128, 171, 214, 256};
        const float inv[6] = {1.f/43.f, 1.f/44.f, 1.f/43.f, 1.f/43.f, 1.f/44.f, 1.f/43.f};
        int row = tid / 6, q = tid - row*6;
        int swz = (row & 7) << 4;
        float s = 0.f;
        for (int c = sb[q]; c < eb[q]; ++c)
            s += (float)(*(const _Float16*)((const char*)aHi + row*512 + ((c*2) ^ swz)));
        int nn = (int)(r0 & 4095) + row;
        Pout[(size_t)b*6*cN + nn*6 + q] = s * inv[q];
    }
}

// ---------------------------------------------------------------------------
// DHHP: both transforms fused; Givens recomputed per block from P.
// ---------------------------------------------------------------------------
__global__ __launch_bounds__(256) void dhhp_kernel(
    const float* __restrict__ x, const float* __restrict__ P,
    const float2* __restrict__ DIAG, float* __restrict__ outf,
    unsigned long long out_floats, int mode)
{
    __shared__ float  xsr[40*64];
    __shared__ float2 bufA[38*64];
    __shared__ float2 bufB[36*64];
    __shared__ float2 cA[38], cBv[38], cC[38], cDg[36];
    __shared__ G4 uG[39], lG[39];

    const int tid = threadIdx.x;
    const int n0 = blockIdx.x * 32;
    const int d0 = blockIdx.y * 64;
    const int b  = blockIdx.z;
    const size_t bbase = (size_t)b * cN;
    const int b6 = b * 6 * cN;
    const float2 z2 = make_float2(0.f, 0.f);

    for (int idx = tid; idx < 40*64; idx += 256) {
        int r = idx >> 6, d = idx & 63;
        int m = n0 - 4 + r;
        float v = 0.f;
        if (m >= 0 && m < cN) v = x[(bbase + m)*cD + d0 + d];
        xsr[idx] = v;
    }
    if (tid < 78) {
        int t = (tid < 39) ? tid : tid - 39;
        int j = n0 - 4 + t;
        G4 g; g.ii = g.ij = g.ji = g.jj = z2;
        if (j >= 0 && j <= cN-2) {
            if (tid < 39) g = givens_f(P[b6+3*cN+j], P[b6+4*cN+j], P[b6+5*cN+j]);   // u[j]
            else          g = givens_f(P[b6+j+1],    P[b6+cN+j+1], P[b6+2*cN+j+1]); // l[j]
        }
        if (tid < 39) uG[t] = g; else lG[t] = g;
    }
    __syncthreads();

    if (tid < 38) {
        int m = n0 - 3 + tid;
        float2 A=z2, Bv=z2, C=z2;
        if (m >= 0 && m < cN) {
            if (m == 0)         { Bv = uG[tid+1].ii; C = uG[tid+1].ij; }
            else if (m == cN-1) { A = uG[tid].ji; Bv = uG[tid].jj; }
            else { A = uG[tid].ji; Bv = cmul(uG[tid].jj, uG[tid+1].ii); C = cmul(uG[tid].jj, uG[tid+1].ij); }
        }
        cA[tid]=A; cBv[tid]=Bv; cC[tid]=C;
    }
    __syncthreads();
    for (int idx = tid; idx < 38*64; idx += 256) {
        int r = idx >> 6;
        float x0 = xsr[idx], x1 = xsr[idx+64], x2 = xsr[idx+128];
        float2 A = cA[r], Bv = cBv[r], C = cC[r];
        bufA[idx] = make_float2(A.x*x0 + Bv.x*x1 + C.x*x2,
                                A.y*x0 + Bv.y*x1 + C.y*x2);
    }
    __syncthreads();

    if (tid < 36) {
        int m = n0 - 2 + tid;
        float2 A=z2, Bv=z2, C=z2, Dg=z2;
        if (m >= 0 && m < cN) {
            Dg = DIAG[bbase + m];
            if (m == 0)         { Bv = lG[tid+2].ii; C = lG[tid+2].ij; }
            else if (m == cN-1) { A = lG[tid+1].ji; Bv = lG[tid+1].jj; }
            else { A = cmul(lG[tid+2].ii, lG[tid+1].ji); Bv = cmul(lG[tid+2].ii, lG[tid+1].jj); C = lG[tid+2].ij; }
        }
        cA[tid]=A; cBv[tid]=Bv; cC[tid]=C; cDg[tid]=Dg;
    }
    __syncthreads();
    for (int idx = tid; idx < 36*64; idx += 256) {
        int r = idx >> 6;
        float2 y0 = bufA[idx], y1 = bufA[idx+64], y2 = bufA[idx+128];
        float2 zv = cmul(cA[r], y0);
        zv = cfma2(cBv[r], y1, zv);
        zv = cfma2(cC[r], y2, zv);
        bufB[idx] = cmul(cDg[r], zv);
    }
    __syncthreads();

    if (tid < 34) {
        int m = n0 - 1 + tid;
        float2 A=z2, Bv=z2, C=z2;
        if (m >= 0 && m < cN) {
            if (m == 0)         { Bv = uG[tid+3].jj; C = cneg(uG[tid+3].ij); }
            else if (m == cN-1) { A = cneg(uG[tid+2].ji); Bv = uG[tid+2].ii; }
            else { A = cneg(uG[tid+2].ji); Bv = cmul(uG[tid+2].ii, uG[tid+3].jj); C = cneg(cmul(uG[tid+2].ii, uG[tid+3].ij)); }
        }
        cA[tid]=A; cBv[tid]=Bv; cC[tid]=C;
    }
    __syncthreads();
    for (int idx = tid; idx < 34*64; idx += 256) {
        int r = idx >> 6;
        float2 zv0 = bufB[idx], zv1 = bufB[idx+64], zv2 = bufB[idx+128];
        float2 w = cmul(cA[r], zv0);
        w = cfma2(cBv[r], zv1, w);
        w = cfma2(cC[r], zv2, w);
        bufA[idx] = w;
    }
    __syncthreads();

    if (tid < 32) {
        int m = n0 + tid;
        float2 A=z2, Bv=z2, C=z2;
        if (m == 0)         { Bv = lG[tid+4].jj; C = cneg(lG[tid+4].ij); }
        else if (m == cN-1) { A = cneg(lG[tid+3].ji); Bv = lG[tid+3].ii; }
        else { A = cneg(cmul(lG[tid+4].jj, lG[tid+3].ji)); Bv = cmul(lG[tid+4].jj, lG[tid+3].ii); C = cneg(lG[tid+4].ij); }
        cA[tid]=A; cBv[tid]=Bv; cC[tid]=C;
    }
    __syncthreads();
    for (int idx = tid; idx < 32*64; idx += 256) {
        int r = idx >> 6, d = idx & 63;
        float2 w0 = bufA[idx], w1 = bufA[idx+64], w2 = bufA[idx+128];
        float2 o = cmul(cA[r], w0);
        o = cfma2(cBv[r], w1, o);
        o = cfma2(cC[r], w2, o);
        unsigned long long ci = (unsigned long long)((bbase + n0 + r)*(size_t)cD + d0 + d);
        if (mode == 0) {
            if (ci < out_floats) outf[ci] = o.x;
        } else {
            if (2ULL*ci + 2ULL <= out_floats) ((float2*)outf)[ci] = o;
        }
    }
}

// ---------------------------------------------------------------------------
extern "C" void kernel_launch(void* const* d_in, const int* in_sizes, int n_in,
                              void* d_out, int out_size, void* d_ws, size_t ws_size,
                              hipStream_t stream)
{
    const int expect[12] = { cBN*cD, cD*cD, cD, 1, cD*cD, cD,
                             cD*cD, cD, 1, cD*cD, cD, cB*9 };
    bool ok = (n_in == 12);
    if (ok) for (int i = 0; i < 12; ++i) ok = ok && (in_sizes[i] == expect[i]);
    if (!ok) {
        sentinel_kernel<<<1, 1, 0, stream>>>((float*)d_out, out_size, 1.0e6f);
        return;
    }
    const size_t pBytes = (size_t)cB * 6 * cN * sizeof(float);       // 768 KB
    const size_t dBytes = (size_t)cBN * sizeof(float2);              // 256 KB
    const size_t wBytes = (size_t)8 * 65536 * sizeof(_Float16);      // 1 MB
    if (d_ws == nullptr || ws_size < pBytes + dBytes + wBytes) {
        sentinel_kernel<<<1, 1, 0, stream>>>((float*)d_out, out_size, 2.0e6f);
        return;
    }
    int mode;
    if (out_size == cBN * cD)          mode = 0;
    else if (out_size == 2 * cBN * cD) mode = 1;
    else {
        sentinel_kernel<<<1, 1, 0, stream>>>((float*)d_out, out_size, 3.0e6f);
        return;
    }

    const float* x     = (const float*)d_in[0];
    const float* ev_w1 = (const float*)d_in[1];
    const float* ev_b1 = (const float*)d_in[2];
    const float* ev_g  = (const float*)d_in[3];
    const float* ev_w2 = (const float*)d_in[4];
    const float* ev_b2 = (const float*)d_in[5];
    const float* hp_w1 = (const float*)d_in[6];
    const float* hp_b1 = (const float*)d_in[7];
    const float* hp_g  = (const float*)d_in[8];
    const float* hp_w2 = (const float*)d_in[9];
    const float* hp_b2 = (const float*)d_in[10];
    const float* cheb  = (const float*)d_in[11];

    float*     P    = (float*)d_ws;
    float2*    DIAG = (float2*)((char*)d_ws + pBytes);
    _Float16*  W16  = (_Float16*)((char*)d_ws + pBytes + dBytes);

    wcvt_kernel<<<dim3(256), 256, 0, stream>>>(ev_w1, ev_w2, hp_w1, hp_w2, W16);
    siren_mfma<<<dim3(cBN/32), 256, 0, stream>>>(x, W16, ev_b1, ev_g, ev_b2,
                                                 hp_b1, hp_g, hp_b2, cheb, P, DIAG);
    dhhp_kernel<<<dim3(cN/32, cD/64, cB), 256, 0, stream>>>(x, P, DIAG, (float*)d_out,
                                                            (unsigned long long)out_size,
                                                            mode);
}

// Round 6
// 174.090 us; speedup vs baseline: 5.7389x; 1.3798x over previous
//
#include <hip/hip_runtime.h>
#include <math.h>

typedef __attribute__((ext_vector_type(8))) _Float16 f16x8;
typedef __attribute__((ext_vector_type(4))) float    f32x4;

static constexpr int cB  = 8;
static constexpr int cN  = 4096;
static constexpr int cD  = 256;
static constexpr int cBN = cB * cN;
#define PI_F 3.14159265358979323846f

__device__ __forceinline__ float2 cmul(float2 a, float2 b) {
    return make_float2(a.x*b.x - a.y*b.y, a.x*b.y + a.y*b.x);
}
__device__ __forceinline__ float2 cfma2(float2 a, float2 b, float2 acc) {
    acc.x += a.x*b.x - a.y*b.y;
    acc.y += a.x*b.y + a.y*b.x;
    return acc;
}
__device__ __forceinline__ float2 cneg(float2 a) { return make_float2(-a.x, -a.y); }

struct G4 { float2 ii, ij, ji, jj; };

__device__ __forceinline__ G4 givens_f(float al, float be, float ga) {
    float ra = (al + be) * (PI_F * 0.5f);
    float rs = (al - be) * (PI_F * 0.5f);
    float gm = ga * (PI_F * 0.5f);
    float sg, cg, sra, cra, srs, crs;
    sincosf(gm, &sg, &cg);
    sincosf(ra, &sra, &cra);
    sincosf(rs, &srs, &crs);
    G4 g;
    g.ii = make_float2( cra*cg, -sra*cg);
    g.ij = make_float2( crs*sg, -srs*sg);
    g.ji = make_float2(-crs*sg, -srs*sg);
    g.jj = make_float2( cra*cg,  sra*cg);
    return g;
}

__global__ void sentinel_kernel(float* out, int n, float v) {
    if (n > 0) out[0] = v;
    if (n > 1) out[1] = v;
}

// ---------------------------------------------------------------------------
// Weight split: fp32 W -> f16 hi/lo pair.
// ---------------------------------------------------------------------------
__global__ __launch_bounds__(256) void wcvt_kernel(
    const float* __restrict__ w0, const float* __restrict__ w1,
    const float* __restrict__ w2, const float* __restrict__ w3,
    _Float16* __restrict__ W16)
{
    int i = blockIdx.x * 256 + threadIdx.x;   // 0..65535
    const float* src[4] = {w0, w1, w2, w3};
    #pragma unroll
    for (int m = 0; m < 4; ++m) {
        float v = src[m][i];
        _Float16 hi = (_Float16)v;
        _Float16 lo = (_Float16)(v - (float)hi);
        W16[(size_t)(2*m)  *65536 + i] = hi;
        W16[(size_t)(2*m+1)*65536 + i] = lo;
    }
}

// ---------------------------------------------------------------------------
// SIREN via MFMA f16 hi/lo split. Block = 64 rows x 256 cols, 4 waves.
// Wave w owns cols [w*64, w*64+64) (4 nt-tiles); 4 mt row-tiles of 16.
// LDS act arrays [64][256] f16, row stride 512B, swizzle byte^((row&7)<<4).
// Weight frags double-buffered (static even/odd sets) to hide L2 latency.
// ---------------------------------------------------------------------------
__device__ __forceinline__ void stage_x16(const float* __restrict__ xrow0,
                                          _Float16* aHi, _Float16* aLo, int tid)
{
    const int row = tid >> 2;          // 0..63
    const int c0  = (tid & 3) * 64;    // 64 cols per thread
    const float4* src = (const float4*)(xrow0 + row*256 + c0);
    const int swz = (row & 7) << 4;
    #pragma unroll
    for (int j = 0; j < 8; ++j) {
        float4 p = src[2*j], q = src[2*j+1];
        float v[8] = {p.x, p.y, p.z, p.w, q.x, q.y, q.z, q.w};
        f16x8 h, l;
        #pragma unroll
        for (int i = 0; i < 8; ++i) {
            _Float16 hi = (_Float16)v[i];
            h[i] = hi;
            l[i] = (_Float16)(v[i] - (float)hi);
        }
        int off = (((c0 + j*8) * 2) ^ swz);
        *(f16x8*)((char*)aHi + row*512 + off) = h;
        *(f16x8*)((char*)aLo + row*512 + off) = l;
    }
}

__device__ __forceinline__ void ld_a(const _Float16* aHi, const _Float16* aLo,
                                     int k0, int lr, int kq, f16x8 ah[4], f16x8 al[4])
{
    #pragma unroll
    for (int mt = 0; mt < 4; ++mt) {
        int row = mt*16 + lr;
        int off = ((k0*2 + kq*16) ^ ((row & 7) << 4));
        ah[mt] = *(const f16x8*)((const char*)aHi + row*512 + off);
        al[mt] = *(const f16x8*)((const char*)aLo + row*512 + off);
    }
}

__device__ __forceinline__ void ld_w(const _Float16* __restrict__ wHi,
                                     const _Float16* __restrict__ wLo,
                                     int k0, int w, int lr, int kq,
                                     f16x8 bh[4], f16x8 bl[4])
{
    #pragma unroll
    for (int nt = 0; nt < 4; ++nt) {
        int col = w*64 + nt*16 + lr;
        bh[nt] = *(const f16x8*)(wHi + col*256 + k0 + kq*8);
        bl[nt] = *(const f16x8*)(wLo + col*256 + k0 + kq*8);
    }
}

__device__ __forceinline__ void do_mfma(const f16x8 ah[4], const f16x8 al[4],
                                        const f16x8 bh[4], const f16x8 bl[4],
                                        f32x4 acc[4][4])
{
    #pragma unroll
    for (int mt = 0; mt < 4; ++mt)
        #pragma unroll
        for (int nt = 0; nt < 4; ++nt) {
            acc[mt][nt] = __builtin_amdgcn_mfma_f32_16x16x32_f16(al[mt], bh[nt], acc[mt][nt], 0, 0, 0);
            acc[mt][nt] = __builtin_amdgcn_mfma_f32_16x16x32_f16(ah[mt], bl[nt], acc[mt][nt], 0, 0, 0);
            acc[mt][nt] = __builtin_amdgcn_mfma_f32_16x16x32_f16(ah[mt], bh[nt], acc[mt][nt], 0, 0, 0);
        }
}

__device__ __forceinline__ void gemm64(const _Float16* aHi, const _Float16* aLo,
                                       const _Float16* __restrict__ wHi,
                                       const _Float16* __restrict__ wLo,
                                       int w, int lr, int kq, f32x4 acc[4][4])
{
    f16x8 ah[4], al[4];
    f16x8 bh0[4], bl0[4], bh1[4], bl1[4];
    ld_w(wHi, wLo, 0, w, lr, kq, bh0, bl0);
    #pragma unroll
    for (int kk = 0; kk < 8; ++kk) {
        ld_a(aHi, aLo, kk*32, lr, kq, ah, al);
        if ((kk & 1) == 0) {
            if (kk < 7) ld_w(wHi, wLo, (kk+1)*32, w, lr, kq, bh1, bl1);
            do_mfma(ah, al, bh0, bl0, acc);
        } else {
            if (kk < 7) ld_w(wHi, wLo, (kk+1)*32, w, lr, kq, bh0, bl0);
            do_mfma(ah, al, bh1, bl1, acc);
        }
    }
}

__global__ __launch_bounds__(256) void siren_mfma(
    const float* __restrict__ x, const _Float16* __restrict__ W16,
    const float* __restrict__ ev_b1, const float* __restrict__ ev_g,
    const float* __restrict__ ev_b2,
    const float* __restrict__ hp_b1, const float* __restrict__ hp_g,
    const float* __restrict__ hp_b2,
    const float* __restrict__ cheb,
    float* __restrict__ Pout, float2* __restrict__ DIAG)
{
    __shared__ _Float16 aHi[64*256];
    __shared__ _Float16 aLo[64*256];
    __shared__ float red[4][64];

    const int tid  = threadIdx.x;
    const int w    = tid >> 6;
    const int lane = tid & 63;
    const int lr   = lane & 15;
    const int kq   = lane >> 4;
    const size_t r0 = (size_t)blockIdx.x * 64;
    const int b = (int)(r0 >> 12);

    const _Float16* ev1h = W16 + 0*65536; const _Float16* ev1l = W16 + 1*65536;
    const _Float16* ev2h = W16 + 2*65536; const _Float16* ev2l = W16 + 3*65536;
    const _Float16* hp1h = W16 + 4*65536; const _Float16* hp1l = W16 + 5*65536;
    const _Float16* hp2h = W16 + 6*65536; const _Float16* hp2l = W16 + 7*65536;

    f32x4 acc[4][4];

    // ===================== EV layer 1 =====================
    stage_x16(x + r0*256, aHi, aLo, tid);
    __syncthreads();
    #pragma unroll
    for (int mt = 0; mt < 4; ++mt)
        #pragma unroll
        for (int nt = 0; nt < 4; ++nt) acc[mt][nt] = (f32x4)(0.f);
    gemm64(aHi, aLo, ev1h, ev1l, w, lr, kq, acc);
    {   // sin + ScaleNorm -> act LDS (hi/lo)
        float bv[4];
        #pragma unroll
        for (int nt = 0; nt < 4; ++nt) bv[nt] = ev_b1[w*64 + nt*16 + lr];
        float sv[4][4][4], rn[4][4];
        #pragma unroll
        for (int mt = 0; mt < 4; ++mt)
            #pragma unroll
            for (int r = 0; r < 4; ++r) {
                float s = 0.f;
                #pragma unroll
                for (int nt = 0; nt < 4; ++nt) {
                    float v = __sinf(acc[mt][nt][r] + bv[nt]);
                    sv[mt][nt][r] = v; s += v*v;
                }
                rn[mt][r] = s;
            }
        #pragma unroll
        for (int mk = 1; mk < 16; mk <<= 1)
            #pragma unroll
            for (int mt = 0; mt < 4; ++mt)
                #pragma unroll
                for (int r = 0; r < 4; ++r) rn[mt][r] += __shfl_xor(rn[mt][r], mk);
        if (lr == 0)
            #pragma unroll
            for (int mt = 0; mt < 4; ++mt)
                #pragma unroll
                for (int r = 0; r < 4; ++r) red[w][mt*16 + kq*4 + r] = rn[mt][r];
        __syncthreads();   // red visible; all GEMM1 LDS reads done
        float g = ev_g[0];
        #pragma unroll
        for (int mt = 0; mt < 4; ++mt)
            #pragma unroll
            for (int r = 0; r < 4; ++r) {
                int row = mt*16 + kq*4 + r;
                float tot = red[0][row] + red[1][row] + red[2][row] + red[3][row];
                float sc = g / fmaxf(sqrtf(tot), 1e-5f);
                int swz = (row & 7) << 4;
                #pragma unroll
                for (int nt = 0; nt < 4; ++nt) {
                    float v = sv[mt][nt][r] * sc;
                    _Float16 hi = (_Float16)v;
                    _Float16 lo = (_Float16)(v - (float)hi);
                    int col = w*64 + nt*16 + lr;
                    int off = ((col*2) ^ swz);
                    *(_Float16*)((char*)aHi + row*512 + off) = hi;
                    *(_Float16*)((char*)aLo + row*512 + off) = lo;
                }
            }
    }
    __syncthreads();

    // ===================== EV layer 2 -> eig -> DIAG =====================
    #pragma unroll
    for (int mt = 0; mt < 4; ++mt)
        #pragma unroll
        for (int nt = 0; nt < 4; ++nt) acc[mt][nt] = (f32x4)(0.f);
    gemm64(aHi, aLo, ev2h, ev2l, w, lr, kq, acc);
    {
        float bv[4];
        #pragma unroll
        for (int nt = 0; nt < 4; ++nt) bv[nt] = ev_b2[w*64 + nt*16 + lr];
        float es[4][4];
        #pragma unroll
        for (int mt = 0; mt < 4; ++mt)
            #pragma unroll
            for (int r = 0; r < 4; ++r) {
                float s = 0.f;
                #pragma unroll
                for (int nt = 0; nt < 4; ++nt) s += __sinf(acc[mt][nt][r] + bv[nt]);
                es[mt][r] = s;
            }
        #pragma unroll
        for (int mk = 1; mk < 16; mk <<= 1)
            #pragma unroll
            for (int mt = 0; mt < 4; ++mt)
                #pragma unroll
                for (int r = 0; r < 4; ++r) es[mt][r] += __shfl_xor(es[mt][r], mk);
        if (lr == 0)
            #pragma unroll
            for (int mt = 0; mt < 4; ++mt)
                #pragma unroll
                for (int r = 0; r < 4; ++r) red[w][mt*16 + kq*4 + r] = es[mt][r];
        __syncthreads();   // red visible; all GEMM2 LDS reads done
        if (tid < 64) {
            int row = tid;
            float ev = (red[0][row] + red[1][row] + red[2][row] + red[3][row]) * (1.f/256.f);
            float dmp[9];
            {
                const double c = 3.14159265358979323846 / 10.0;
                double sc = sin(c), cc = cos(c);
                dmp[0] = 1.f;
                for (int k = 1; k < 9; ++k)
                    dmp[k] = (float)(((10.0 - k) * sc * cos(k*c) + cc * sin(k*c)) / (10.0 * sc));
            }
            const float* cf = cheb + b*9;
            float t0 = 1.f, t1 = ev;
            float filt = cf[0] + ev * cf[1] * dmp[1];
            #pragma unroll
            for (int k = 2; k < 9; ++k) {
                float t2 = 2.f*ev*t1 - t0;
                filt += t2 * cf[k] * dmp[k];
                t0 = t1; t1 = t2;
            }
            float sp, cp;
            sincosf(PI_F * ev, &sp, &cp);
            DIAG[r0 + row] = make_float2(filt*cp, filt*sp);
        }
    }

    // ===================== HP layer 1 =====================
    stage_x16(x + r0*256, aHi, aLo, tid);   // safe: barrier above drained GEMM2 reads
    __syncthreads();
    #pragma unroll
    for (int mt = 0; mt < 4; ++mt)
        #pragma unroll
        for (int nt = 0; nt < 4; ++nt) acc[mt][nt] = (f32x4)(0.f);
    gemm64(aHi, aLo, hp1h, hp1l, w, lr, kq, acc);
    {
        float bv[4];
        #pragma unroll
        for (int nt = 0; nt < 4; ++nt) bv[nt] = hp_b1[w*64 + nt*16 + lr];
        float sv[4][4][4], rn[4][4];
        #pragma unroll
        for (int mt = 0; mt < 4; ++mt)
            #pragma unroll
            for (int r = 0; r < 4; ++r) {
                float s = 0.f;
                #pragma unroll
                for (int nt = 0; nt < 4; ++nt) {
                    float v = __sinf(acc[mt][nt][r] + bv[nt]);
                    sv[mt][nt][r] = v; s += v*v;
                }
                rn[mt][r] = s;
            }
        #pragma unroll
        for (int mk = 1; mk < 16; mk <<= 1)
            #pragma unroll
            for (int mt = 0; mt < 4; ++mt)
                #pragma unroll
                for (int r = 0; r < 4; ++r) rn[mt][r] += __shfl_xor(rn[mt][r], mk);
        if (lr == 0)
            #pragma unroll
            for (int mt = 0; mt < 4; ++mt)
                #pragma unroll
                for (int r = 0; r < 4; ++r) red[w][mt*16 + kq*4 + r] = rn[mt][r];
        __syncthreads();
        float g = hp_g[0];
        #pragma unroll
        for (int mt = 0; mt < 4; ++mt)
            #pragma unroll
            for (int r = 0; r < 4; ++r) {
                int row = mt*16 + kq*4 + r;
                float tot = red[0][row] + red[1][row] + red[2][row] + red[3][row];
                float sc = g / fmaxf(sqrtf(tot), 1e-5f);
                int swz = (row & 7) << 4;
                #pragma unroll
                for (int nt = 0; nt < 4; ++nt) {
                    float v = sv[mt][nt][r] * sc;
                    _Float16 hi = (_Float16)v;
                    _Float16 lo = (_Float16)(v - (float)hi);
                    int col = w*64 + nt*16 + lr;
                    int off = ((col*2) ^ swz);
                    *(_Float16*)((char*)aHi + row*512 + off) = hi;
                    *(_Float16*)((char*)aLo + row*512 + off) = lo;
                }
            }
    }
    __syncthreads();

    // ===================== HP layer 2 -> pool -> Pout =====================
    #pragma unroll
    for (int mt = 0; mt < 4; ++mt)
        #pragma unroll
        for (int nt = 0; nt < 4; ++nt) acc[mt][nt] = (f32x4)(0.f);
    gemm64(aHi, aLo, hp2h, hp2l, w, lr, kq, acc);
    __syncthreads();   // all GEMM reads done before overwrite
    {
        float bv[4];
        #pragma unroll
        for (int nt = 0; nt < 4; ++nt) bv[nt] = hp_b2[w*64 + nt*16 + lr];
        #pragma unroll
        for (int mt = 0; mt < 4; ++mt)
            #pragma unroll
            for (int r = 0; r < 4; ++r) {
                int row = mt*16 + kq*4 + r;
                int swz = (row & 7) << 4;
                #pragma unroll
                for (int nt = 0; nt < 4; ++nt) {
                    float v = __sinf(acc[mt][nt][r] + bv[nt]);
                    int col = w*64 + nt*16 + lr;
                    int off = ((col*2) ^ swz);
                    *(_Float16*)((char*)aHi + row*512 + off) = (_Float16)v;
                }
            }
    }
    __syncthreads();
    {   // AdaptiveAvgPool1d(6), torch bins; flat [B][6N] store
        const int sb[6] = {0, 42, 85, 128, 170, 213};
        const int eb[6] = {43, 86, 128, 171, 214, 256};
        const float inv[6] = {1.f/43.f, 1.f/44.f, 1.f/43.f, 1.f/43.f, 1.f/44.f, 1.f/43.f};
        for (int idx = tid; idx < 384; idx += 256) {
            int row = idx / 6, q = idx - row*6;
            int swz = (row & 7) << 4;
            float s = 0.f;
            for (int c = sb[q]; c < eb[q]; ++c)
                s += (float)(*(const _Float16*)((const char*)aHi + row*512 + ((c*2) ^ swz)));
            int nn = (int)(r0 & 4095) + row;
            Pout[(size_t)b*6*cN + nn*6 + q] = s * inv[q];
        }
    }
}

// ---------------------------------------------------------------------------
// DHHP: both transforms fused; Givens recomputed per block from P.
// ---------------------------------------------------------------------------
__global__ __launch_bounds__(256) void dhhp_kernel(
    const float* __restrict__ x, const float* __restrict__ P,
    const float2* __restrict__ DIAG, float* __restrict__ outf,
    unsigned long long out_floats, int mode)
{
    __shared__ float  xsr[40*64];
    __shared__ float2 bufA[38*64];
    __shared__ float2 bufB[36*64];
    __shared__ float2 cA[38], cBv[38], cC[38], cDg[36];
    __shared__ G4 uG[39], lG[39];

    const int tid = threadIdx.x;
    const int n0 = blockIdx.x * 32;
    const int d0 = blockIdx.y * 64;
    const int b  = blockIdx.z;
    const size_t bbase = (size_t)b * cN;
    const int b6 = b * 6 * cN;
    const float2 z2 = make_float2(0.f, 0.f);

    for (int idx = tid; idx < 40*64; idx += 256) {
        int r = idx >> 6, d = idx & 63;
        int m = n0 - 4 + r;
        float v = 0.f;
        if (m >= 0 && m < cN) v = x[(bbase + m)*cD + d0 + d];
        xsr[idx] = v;
    }
    if (tid < 78) {
        int t = (tid < 39) ? tid : tid - 39;
        int j = n0 - 4 + t;
        G4 g; g.ii = g.ij = g.ji = g.jj = z2;
        if (j >= 0 && j <= cN-2) {
            if (tid < 39) g = givens_f(P[b6+3*cN+j], P[b6+4*cN+j], P[b6+5*cN+j]);   // u[j]
            else          g = givens_f(P[b6+j+1],    P[b6+cN+j+1], P[b6+2*cN+j+1]); // l[j]
        }
        if (tid < 39) uG[t] = g; else lG[t] = g;
    }
    __syncthreads();

    if (tid < 38) {
        int m = n0 - 3 + tid;
        float2 A=z2, Bv=z2, C=z2;
        if (m >= 0 && m < cN) {
            if (m == 0)         { Bv = uG[tid+1].ii; C = uG[tid+1].ij; }
            else if (m == cN-1) { A = uG[tid].ji; Bv = uG[tid].jj; }
            else { A = uG[tid].ji; Bv = cmul(uG[tid].jj, uG[tid+1].ii); C = cmul(uG[tid].jj, uG[tid+1].ij); }
        }
        cA[tid]=A; cBv[tid]=Bv; cC[tid]=C;
    }
    __syncthreads();
    for (int idx = tid; idx < 38*64; idx += 256) {
        int r = idx >> 6;
        float x0 = xsr[idx], x1 = xsr[idx+64], x2 = xsr[idx+128];
        float2 A = cA[r], Bv = cBv[r], C = cC[r];
        bufA[idx] = make_float2(A.x*x0 + Bv.x*x1 + C.x*x2,
                                A.y*x0 + Bv.y*x1 + C.y*x2);
    }
    __syncthreads();

    if (tid < 36) {
        int m = n0 - 2 + tid;
        float2 A=z2, Bv=z2, C=z2, Dg=z2;
        if (m >= 0 && m < cN) {
            Dg = DIAG[bbase + m];
            if (m == 0)         { Bv = lG[tid+2].ii; C = lG[tid+2].ij; }
            else if (m == cN-1) { A = lG[tid+1].ji; Bv = lG[tid+1].jj; }
            else { A = cmul(lG[tid+2].ii, lG[tid+1].ji); Bv = cmul(lG[tid+2].ii, lG[tid+1].jj); C = lG[tid+2].ij; }
        }
        cA[tid]=A; cBv[tid]=Bv; cC[tid]=C; cDg[tid]=Dg;
    }
    __syncthreads();
    for (int idx = tid; idx < 36*64; idx += 256) {
        int r = idx >> 6;
        float2 y0 = bufA[idx], y1 = bufA[idx+64], y2 = bufA[idx+128];
        float2 zv = cmul(cA[r], y0);
        zv = cfma2(cBv[r], y1, zv);
        zv = cfma2(cC[r], y2, zv);
        bufB[idx] = cmul(cDg[r], zv);
    }
    __syncthreads();

    if (tid < 34) {
        int m = n0 - 1 + tid;
        float2 A=z2, Bv=z2, C=z2;
        if (m >= 0 && m < cN) {
            if (m == 0)         { Bv = uG[tid+3].jj; C = cneg(uG[tid+3].ij); }
            else if (m == cN-1) { A = cneg(uG[tid+2].ji); Bv = uG[tid+2].ii; }
            else { A = cneg(uG[tid+2].ji); Bv = cmul(uG[tid+2].ii, uG[tid+3].jj); C = cneg(cmul(uG[tid+2].ii, uG[tid+3].ij)); }
        }
        cA[tid]=A; cBv[tid]=Bv; cC[tid]=C;
    }
    __syncthreads();
    for (int idx = tid; idx < 34*64; idx += 256) {
        int r = idx >> 6;
        float2 zv0 = bufB[idx], zv1 = bufB[idx+64], zv2 = bufB[idx+128];
        float2 w = cmul(cA[r], zv0);
        w = cfma2(cBv[r], zv1, w);
        w = cfma2(cC[r], zv2, w);
        bufA[idx] = w;
    }
    __syncthreads();

    if (tid < 32) {
        int m = n0 + tid;
        float2 A=z2, Bv=z2, C=z2;
        if (m == 0)         { Bv = lG[tid+4].jj; C = cneg(lG[tid+4].ij); }
        else if (m == cN-1) { A = cneg(lG[tid+3].ji); Bv = lG[tid+3].ii; }
        else { A = cneg(cmul(lG[tid+4].jj, lG[tid+3].ji)); Bv = cmul(lG[tid+4].jj, lG[tid+3].ii); C = cneg(lG[tid+4].ij); }
        cA[tid]=A; cBv[tid]=Bv; cC[tid]=C;
    }
    __syncthreads();
    for (int idx = tid; idx < 32*64; idx += 256) {
        int r = idx >> 6, d = idx & 63;
        float2 w0 = bufA[idx], w1 = bufA[idx+64], w2 = bufA[idx+128];
        float2 o = cmul(cA[r], w0);
        o = cfma2(cBv[r], w1, o);
        o = cfma2(cC[r], w2, o);
        unsigned long long ci = (unsigned long long)((bbase + n0 + r)*(size_t)cD + d0 + d);
        if (mode == 0) {
            if (ci < out_floats) outf[ci] = o.x;
        } else {
            if (2ULL*ci + 2ULL <= out_floats) ((float2*)outf)[ci] = o;
        }
    }
}

// ---------------------------------------------------------------------------
extern "C" void kernel_launch(void* const* d_in, const int* in_sizes, int n_in,
                              void* d_out, int out_size, void* d_ws, size_t ws_size,
                              hipStream_t stream)
{
    const int expect[12] = { cBN*cD, cD*cD, cD, 1, cD*cD, cD,
                             cD*cD, cD, 1, cD*cD, cD, cB*9 };
    bool ok = (n_in == 12);
    if (ok) for (int i = 0; i < 12; ++i) ok = ok && (in_sizes[i] == expect[i]);
    if (!ok) {
        sentinel_kernel<<<1, 1, 0, stream>>>((float*)d_out, out_size, 1.0e6f);
        return;
    }
    const size_t pBytes = (size_t)cB * 6 * cN * sizeof(float);       // 768 KB
    const size_t dBytes = (size_t)cBN * sizeof(float2);              // 256 KB
    const size_t wBytes = (size_t)8 * 65536 * sizeof(_Float16);      // 1 MB
    if (d_ws == nullptr || ws_size < pBytes + dBytes + wBytes) {
        sentinel_kernel<<<1, 1, 0, stream>>>((float*)d_out, out_size, 2.0e6f);
        return;
    }
    int mode;
    if (out_size == cBN * cD)          mode = 0;
    else if (out_size == 2 * cBN * cD) mode = 1;
    else {
        sentinel_kernel<<<1, 1, 0, stream>>>((float*)d_out, out_size, 3.0e6f);
        return;
    }

    const float* x     = (const float*)d_in[0];
    const float* ev_w1 = (const float*)d_in[1];
    const float* ev_b1 = (const float*)d_in[2];
    const float* ev_g  = (const float*)d_in[3];
    const float* ev_w2 = (const float*)d_in[4];
    const float* ev_b2 = (const float*)d_in[5];
    const float* hp_w1 = (const float*)d_in[6];
    const float* hp_b1 = (const float*)d_in[7];
    const float* hp_g  = (const float*)d_in[8];
    const float* hp_w2 = (const float*)d_in[9];
    const float* hp_b2 = (const float*)d_in[10];
    const float* cheb  = (const float*)d_in[11];

    float*     P    = (float*)d_ws;
    float2*    DIAG = (float2*)((char*)d_ws + pBytes);
    _Float16*  W16  = (_Float16*)((char*)d_ws + pBytes + dBytes);

    wcvt_kernel<<<dim3(256), 256, 0, stream>>>(ev_w1, ev_w2, hp_w1, hp_w2, W16);
    siren_mfma<<<dim3(cBN/64), 256, 0, stream>>>(x, W16, ev_b1, ev_g, ev_b2,
                                                 hp_b1, hp_g, hp_b2, cheb, P, DIAG);
    dhhp_kernel<<<dim3(cN/32, cD/64, cB), 256, 0, stream>>>(x, P, DIAG, (float*)d_out,
                                                            (unsigned long long)out_size,
                                                            mode);
}

// Round 7
// 169.219 us; speedup vs baseline: 5.9041x; 1.0288x over previous
//
#include <hip/hip_runtime.h>
#include <math.h>

typedef __attribute__((ext_vector_type(8))) _Float16 f16x8;
typedef __attribute__((ext_vector_type(4))) float    f32x4;

static constexpr int cB  = 8;
static constexpr int cN  = 4096;
static constexpr int cD  = 256;
static constexpr int cBN = cB * cN;
#define PI_F 3.14159265358979323846f

__device__ __forceinline__ float2 cmul(float2 a, float2 b) {
    return make_float2(a.x*b.x - a.y*b.y, a.x*b.y + a.y*b.x);
}
__device__ __forceinline__ float2 cfma2(float2 a, float2 b, float2 acc) {
    acc.x += a.x*b.x - a.y*b.y;
    acc.y += a.x*b.y + a.y*b.x;
    return acc;
}
__device__ __forceinline__ float2 cneg(float2 a) { return make_float2(-a.x, -a.y); }

struct G4 { float2 ii, ij, ji, jj; };

__device__ __forceinline__ G4 givens_f(float al, float be, float ga) {
    float ra = (al + be) * (PI_F * 0.5f);
    float rs = (al - be) * (PI_F * 0.5f);
    float gm = ga * (PI_F * 0.5f);
    float sg, cg, sra, cra, srs, crs;
    sincosf(gm, &sg, &cg);
    sincosf(ra, &sra, &cra);
    sincosf(rs, &srs, &crs);
    G4 g;
    g.ii = make_float2( cra*cg, -sra*cg);
    g.ij = make_float2( crs*sg, -srs*sg);
    g.ji = make_float2(-crs*sg, -srs*sg);
    g.jj = make_float2( cra*cg,  sra*cg);
    return g;
}

__global__ void sentinel_kernel(float* out, int n, float v) {
    if (n > 0) out[0] = v;
    if (n > 1) out[1] = v;
}

// ---------------------------------------------------------------------------
// Weight split: fp32 W -> f16 hi/lo pair.
// ---------------------------------------------------------------------------
__global__ __launch_bounds__(256) void wcvt_kernel(
    const float* __restrict__ w0, const float* __restrict__ w1,
    const float* __restrict__ w2, const float* __restrict__ w3,
    _Float16* __restrict__ W16)
{
    int i = blockIdx.x * 256 + threadIdx.x;   // 0..65535
    const float* src[4] = {w0, w1, w2, w3};
    #pragma unroll
    for (int m = 0; m < 4; ++m) {
        float v = src[m][i];
        _Float16 hi = (_Float16)v;
        _Float16 lo = (_Float16)(v - (float)hi);
        W16[(size_t)(2*m)  *65536 + i] = hi;
        W16[(size_t)(2*m+1)*65536 + i] = lo;
    }
}

// ---------------------------------------------------------------------------
// SIREN via MFMA f16 hi/lo split. Block = 64 rows x 256 cols, 8 waves.
// Wave w owns cols [w*32, w*32+32) (2 nt-tiles); 4 mt row-tiles of 16.
// LDS act [64][256] f16 hi/lo, row stride 512B, swizzle byte^((row&7)<<4).
// launch_bounds(512,4): target <=128 VGPR -> 4 waves/SIMD (2 blocks/CU).
// ---------------------------------------------------------------------------
__device__ __forceinline__ void stage_x16(const float* __restrict__ xrow0,
                                          _Float16* aHi, _Float16* aLo, int tid)
{
    const int row = tid >> 3;          // 0..63
    const int c0  = (tid & 7) * 32;    // 32 cols per thread
    const float4* src = (const float4*)(xrow0 + row*256 + c0);
    const int swz = (row & 7) << 4;
    #pragma unroll
    for (int j = 0; j < 4; ++j) {
        float4 p = src[2*j], q = src[2*j+1];
        float v[8] = {p.x, p.y, p.z, p.w, q.x, q.y, q.z, q.w};
        f16x8 h, l;
        #pragma unroll
        for (int i = 0; i < 8; ++i) {
            _Float16 hi = (_Float16)v[i];
            h[i] = hi;
            l[i] = (_Float16)(v[i] - (float)hi);
        }
        int off = (((c0 + j*8) * 2) ^ swz);
        *(f16x8*)((char*)aHi + row*512 + off) = h;
        *(f16x8*)((char*)aLo + row*512 + off) = l;
    }
}

__device__ __forceinline__ void ld_a(const _Float16* aHi, const _Float16* aLo,
                                     int k0, int lr, int kq, f16x8 ah[4], f16x8 al[4])
{
    #pragma unroll
    for (int mt = 0; mt < 4; ++mt) {
        int row = mt*16 + lr;
        int off = ((k0*2 + kq*16) ^ ((row & 7) << 4));
        ah[mt] = *(const f16x8*)((const char*)aHi + row*512 + off);
        al[mt] = *(const f16x8*)((const char*)aLo + row*512 + off);
    }
}

__device__ __forceinline__ void ld_w2(const _Float16* __restrict__ wHi,
                                      const _Float16* __restrict__ wLo,
                                      int k0, int w, int lr, int kq,
                                      f16x8 bh[2], f16x8 bl[2])
{
    #pragma unroll
    for (int nt = 0; nt < 2; ++nt) {
        int col = w*32 + nt*16 + lr;
        bh[nt] = *(const f16x8*)(wHi + col*256 + k0 + kq*8);
        bl[nt] = *(const f16x8*)(wLo + col*256 + k0 + kq*8);
    }
}

__device__ __forceinline__ void do_mfma24(const f16x8 ah[4], const f16x8 al[4],
                                          const f16x8 bh[2], const f16x8 bl[2],
                                          f32x4 acc[4][2])
{
    #pragma unroll
    for (int mt = 0; mt < 4; ++mt)
        #pragma unroll
        for (int nt = 0; nt < 2; ++nt) {
            acc[mt][nt] = __builtin_amdgcn_mfma_f32_16x16x32_f16(al[mt], bh[nt], acc[mt][nt], 0, 0, 0);
            acc[mt][nt] = __builtin_amdgcn_mfma_f32_16x16x32_f16(ah[mt], bl[nt], acc[mt][nt], 0, 0, 0);
            acc[mt][nt] = __builtin_amdgcn_mfma_f32_16x16x32_f16(ah[mt], bh[nt], acc[mt][nt], 0, 0, 0);
        }
}

__device__ __forceinline__ void gemm32(const _Float16* aHi, const _Float16* aLo,
                                       const _Float16* __restrict__ wHi,
                                       const _Float16* __restrict__ wLo,
                                       int w, int lr, int kq, f32x4 acc[4][2])
{
    f16x8 ah[4], al[4];
    f16x8 bh0[2], bl0[2], bh1[2], bl1[2];
    ld_w2(wHi, wLo, 0, w, lr, kq, bh0, bl0);
    #pragma unroll
    for (int kk = 0; kk < 8; ++kk) {
        ld_a(aHi, aLo, kk*32, lr, kq, ah, al);
        if ((kk & 1) == 0) {
            if (kk < 7) ld_w2(wHi, wLo, (kk+1)*32, w, lr, kq, bh1, bl1);
            do_mfma24(ah, al, bh0, bl0, acc);
        } else {
            if (kk < 7) ld_w2(wHi, wLo, (kk+1)*32, w, lr, kq, bh0, bl0);
            do_mfma24(ah, al, bh1, bl1, acc);
        }
    }
}

__global__ __launch_bounds__(512, 4) void siren_mfma(
    const float* __restrict__ x, const _Float16* __restrict__ W16,
    const float* __restrict__ ev_b1, const float* __restrict__ ev_g,
    const float* __restrict__ ev_b2,
    const float* __restrict__ hp_b1, const float* __restrict__ hp_g,
    const float* __restrict__ hp_b2,
    const float* __restrict__ cheb,
    float* __restrict__ Pout, float2* __restrict__ DIAG)
{
    __shared__ _Float16 aHi[64*256];
    __shared__ _Float16 aLo[64*256];
    __shared__ float red[8][64];

    const int tid  = threadIdx.x;
    const int w    = tid >> 6;          // 0..7
    const int lane = tid & 63;
    const int lr   = lane & 15;
    const int kq   = lane >> 4;
    const size_t r0 = (size_t)blockIdx.x * 64;
    const int b = (int)(r0 >> 12);

    for (int net = 0; net < 2; ++net) {
        const _Float16* w1h = W16 + (size_t)(net*4 + 0)*65536;
        const _Float16* w1l = W16 + (size_t)(net*4 + 1)*65536;
        const _Float16* w2h = W16 + (size_t)(net*4 + 2)*65536;
        const _Float16* w2l = W16 + (size_t)(net*4 + 3)*65536;
        const float* b1 = net ? hp_b1 : ev_b1;
        const float* b2 = net ? hp_b2 : ev_b2;
        const float  g  = net ? hp_g[0] : ev_g[0];

        stage_x16(x + r0*256, aHi, aLo, tid);
        __syncthreads();

        f32x4 acc[4][2];
        #pragma unroll
        for (int mt = 0; mt < 4; ++mt)
            #pragma unroll
            for (int nt = 0; nt < 2; ++nt) acc[mt][nt] = (f32x4)(0.f);
        gemm32(aHi, aLo, w1h, w1l, w, lr, kq, acc);

        {   // layer-1 epilogue: sin + ScaleNorm -> act LDS (hi/lo)
            float bv[2] = { b1[w*32 + lr], b1[w*32 + 16 + lr] };
            float sv[4][2][4], rn[4][4];
            #pragma unroll
            for (int mt = 0; mt < 4; ++mt)
                #pragma unroll
                for (int r = 0; r < 4; ++r) {
                    float s = 0.f;
                    #pragma unroll
                    for (int nt = 0; nt < 2; ++nt) {
                        float v = __sinf(acc[mt][nt][r] + bv[nt]);
                        sv[mt][nt][r] = v; s += v*v;
                    }
                    rn[mt][r] = s;
                }
            #pragma unroll
            for (int mk = 1; mk < 16; mk <<= 1)
                #pragma unroll
                for (int mt = 0; mt < 4; ++mt)
                    #pragma unroll
                    for (int r = 0; r < 4; ++r) rn[mt][r] += __shfl_xor(rn[mt][r], mk);
            if (lr == 0)
                #pragma unroll
                for (int mt = 0; mt < 4; ++mt)
                    #pragma unroll
                    for (int r = 0; r < 4; ++r) red[w][mt*16 + kq*4 + r] = rn[mt][r];
            __syncthreads();   // red visible; all gemm-L1 LDS reads done
            #pragma unroll
            for (int mt = 0; mt < 4; ++mt)
                #pragma unroll
                for (int r = 0; r < 4; ++r) {
                    int row = mt*16 + kq*4 + r;
                    float tot = 0.f;
                    #pragma unroll
                    for (int ww = 0; ww < 8; ++ww) tot += red[ww][row];
                    float sc = g / fmaxf(sqrtf(tot), 1e-5f);
                    int swz = (row & 7) << 4;
                    #pragma unroll
                    for (int nt = 0; nt < 2; ++nt) {
                        float v = sv[mt][nt][r] * sc;
                        _Float16 hi = (_Float16)v;
                        _Float16 lo = (_Float16)(v - (float)hi);
                        int col = w*32 + nt*16 + lr;
                        int off = ((col*2) ^ swz);
                        *(_Float16*)((char*)aHi + row*512 + off) = hi;
                        *(_Float16*)((char*)aLo + row*512 + off) = lo;
                    }
                }
        }
        __syncthreads();

        #pragma unroll
        for (int mt = 0; mt < 4; ++mt)
            #pragma unroll
            for (int nt = 0; nt < 2; ++nt) acc[mt][nt] = (f32x4)(0.f);
        gemm32(aHi, aLo, w2h, w2l, w, lr, kq, acc);

        if (net == 0) {   // eig -> DIAG
            float bv[2] = { b2[w*32 + lr], b2[w*32 + 16 + lr] };
            float es[4][4];
            #pragma unroll
            for (int mt = 0; mt < 4; ++mt)
                #pragma unroll
                for (int r = 0; r < 4; ++r) {
                    float s = 0.f;
                    #pragma unroll
                    for (int nt = 0; nt < 2; ++nt) s += __sinf(acc[mt][nt][r] + bv[nt]);
                    es[mt][r] = s;
                }
            #pragma unroll
            for (int mk = 1; mk < 16; mk <<= 1)
                #pragma unroll
                for (int mt = 0; mt < 4; ++mt)
                    #pragma unroll
                    for (int r = 0; r < 4; ++r) es[mt][r] += __shfl_xor(es[mt][r], mk);
            if (lr == 0)
                #pragma unroll
                for (int mt = 0; mt < 4; ++mt)
                    #pragma unroll
                    for (int r = 0; r < 4; ++r) red[w][mt*16 + kq*4 + r] = es[mt][r];
            __syncthreads();   // red visible; all gemm-L2 LDS reads done
            if (tid < 64) {
                int row = tid;
                float tot = 0.f;
                #pragma unroll
                for (int ww = 0; ww < 8; ++ww) tot += red[ww][row];
                float ev = tot * (1.f/256.f);
                float dmp[9];
                {
                    const double c = 3.14159265358979323846 / 10.0;
                    double sc = sin(c), cc = cos(c);
                    dmp[0] = 1.f;
                    for (int k = 1; k < 9; ++k)
                        dmp[k] = (float)(((10.0 - k) * sc * cos(k*c) + cc * sin(k*c)) / (10.0 * sc));
                }
                const float* cf = cheb + b*9;
                float t0 = 1.f, t1 = ev;
                float filt = cf[0] + ev * cf[1] * dmp[1];
                #pragma unroll
                for (int k = 2; k < 9; ++k) {
                    float t2 = 2.f*ev*t1 - t0;
                    filt += t2 * cf[k] * dmp[k];
                    t0 = t1; t1 = t2;
                }
                float sp, cp;
                sincosf(PI_F * ev, &sp, &cp);
                DIAG[r0 + row] = make_float2(filt*cp, filt*sp);
            }
        } else {          // pool -> Pout
            __syncthreads();   // all gemm-L2 LDS reads done before act overwrite
            float bv[2] = { b2[w*32 + lr], b2[w*32 + 16 + lr] };
            #pragma unroll
            for (int mt = 0; mt < 4; ++mt)
                #pragma unroll
                for (int r = 0; r < 4; ++r) {
                    int row = mt*16 + kq*4 + r;
                    int swz = (row & 7) << 4;
                    #pragma unroll
                    for (int nt = 0; nt < 2; ++nt) {
                        float v = __sinf(acc[mt][nt][r] + bv[nt]);
                        int col = w*32 + nt*16 + lr;
                        int off = ((col*2) ^ swz);
                        *(_Float16*)((char*)aHi + row*512 + off) = (_Float16)v;
                    }
                }
            __syncthreads();
            if (tid < 384) {   // AdaptiveAvgPool1d(6), torch bins; flat [B][6N]
                const int sb[6] = {0, 42, 85, 128, 170, 213};
                const int eb[6] = {43, 86, 128, 171, 214, 256};
                const float inv[6] = {1.f/43.f, 1.f/44.f, 1.f/43.f, 1.f/43.f, 1.f/44.f, 1.f/43.f};
                int row = tid / 6, q = tid - row*6;
                int swz = (row & 7) << 4;
                float s = 0.f;
                for (int c = sb[q]; c < eb[q]; ++c)
                    s += (float)(*(const _Float16*)((const char*)aHi + row*512 + ((c*2) ^ swz)));
                int nn = (int)(r0 & 4095) + row;
                Pout[(size_t)b*6*cN + nn*6 + q] = s * inv[q];
            }
        }
    }
}

// ---------------------------------------------------------------------------
// DHHP as one 9-band stencil: T = L' U' D L U composed per row (exact algebra),
// then out[m] = sum_j T[m][j] * x[m-4+j]. One barrier pair, no ping-pong.
// ---------------------------------------------------------------------------
__global__ __launch_bounds__(256) void dhhp_stencil(
    const float* __restrict__ x, const float* __restrict__ P,
    const float2* __restrict__ DIAG, float* __restrict__ outf,
    unsigned long long out_floats, int mode)
{
    __shared__ float  xsr[40*64];
    __shared__ G4 uG[41], lG[41];
    __shared__ float2 cDg[40];
    __shared__ float2 cT[32][9];

    const int tid = threadIdx.x;
    const int n0 = blockIdx.x * 32;
    const int d0 = blockIdx.y * 64;
    const int b  = blockIdx.z;
    const size_t bbase = (size_t)b * cN;
    const int b6 = b * 6 * cN;
    const float2 z2 = make_float2(0.f, 0.f);
    const int jb = n0 - 5;

    for (int idx = tid; idx < 40*64; idx += 256) {
        int r = idx >> 6, d = idx & 63;
        int m = n0 - 4 + r;
        xsr[idx] = (m >= 0 && m < cN) ? x[(bbase + m)*cD + d0 + d] : 0.f;
    }
    if (tid < 82) {
        int t = (tid < 41) ? tid : tid - 41;
        int j = jb + t;
        G4 g; g.ii = g.ij = g.ji = g.jj = z2;
        if (j >= 0 && j <= cN-2) {
            if (tid < 41) g = givens_f(P[b6+3*cN+j], P[b6+4*cN+j], P[b6+5*cN+j]);   // u[j]
            else          g = givens_f(P[b6+j+1],    P[b6+cN+j+1], P[b6+2*cN+j+1]); // l[j]
        }
        if (tid < 41) uG[t] = g; else lG[t] = g;
    } else if (tid < 122) {
        int t = tid - 82;
        int m = n0 - 4 + t;
        cDg[t] = (m >= 0 && m < cN) ? DIAG[bbase + m] : z2;
    }
    __syncthreads();

    if (tid < 32) {
        const int m = n0 + tid;
        // stage tridiagonal coeffs (A,B,C) at global row rr, stage s:
        // s=1: U, s=2: L, s=3: U' (conj-transpose), s=4: L'
        auto scoef = [&](int s, int rr, float2& A, float2& B, float2& C) {
            A = z2; B = z2; C = z2;
            if (rr < 0 || rr >= cN) return;
            if (s == 1) {
                if (rr == 0)         { G4 u0 = uG[0-jb]; B = u0.ii; C = u0.ij; }
                else if (rr == cN-1) { G4 up = uG[rr-1-jb]; A = up.ji; B = up.jj; }
                else { G4 up = uG[rr-1-jb], uc = uG[rr-jb];
                       A = up.ji; B = cmul(up.jj, uc.ii); C = cmul(up.jj, uc.ij); }
            } else if (s == 2) {
                if (rr == 0)         { G4 l0 = lG[0-jb]; B = l0.ii; C = l0.ij; }
                else if (rr == cN-1) { G4 lp = lG[rr-1-jb]; A = lp.ji; B = lp.jj; }
                else { G4 lp = lG[rr-1-jb], lc = lG[rr-jb];
                       A = cmul(lc.ii, lp.ji); B = cmul(lc.ii, lp.jj); C = lc.ij; }
            } else if (s == 3) {
                if (rr == 0)         { G4 u0 = uG[0-jb]; B = u0.jj; C = cneg(u0.ij); }
                else if (rr == cN-1) { G4 up = uG[rr-1-jb]; A = cneg(up.ji); B = up.ii; }
                else { G4 up = uG[rr-1-jb], uc = uG[rr-jb];
                       A = cneg(up.ji); B = cmul(up.ii, uc.jj); C = cneg(cmul(up.ii, uc.ij)); }
            } else {
                if (rr == 0)         { G4 l0 = lG[0-jb]; B = l0.jj; C = cneg(l0.ij); }
                else if (rr == cN-1) { G4 lp = lG[rr-1-jb]; A = cneg(lp.ji); B = lp.ii; }
                else { G4 lp = lG[rr-1-jb], lc = lG[rr-jb];
                       A = cneg(cmul(lc.jj, lp.ji)); B = cmul(lc.jj, lp.ii); C = cneg(lc.ij); }
            }
        };

        float2 wv[9], nw[9];
        #pragma unroll
        for (int k = 0; k < 9; ++k) wv[k] = z2;
        {   // start: row m of L' (offsets -1..1 -> idx 3..5)
            float2 A, B, C; scoef(4, m, A, B, C);
            wv[3] = A; wv[4] = B; wv[5] = C;
        }
        // apply U' : width -> idx 2..6
        #pragma unroll
        for (int k = 0; k < 9; ++k) nw[k] = z2;
        #pragma unroll
        for (int i = 3; i <= 5; ++i) {
            float2 A, B, C; scoef(3, m + i - 4, A, B, C);
            nw[i-1] = cfma2(wv[i], A, nw[i-1]);
            nw[i]   = cfma2(wv[i], B, nw[i]);
            nw[i+1] = cfma2(wv[i], C, nw[i+1]);
        }
        #pragma unroll
        for (int k = 0; k < 9; ++k) wv[k] = nw[k];
        // apply D (diagonal at column rows): idx 2..6
        #pragma unroll
        for (int k = 2; k <= 6; ++k) wv[k] = cmul(wv[k], cDg[tid + k]);
        // apply L : width -> idx 1..7
        #pragma unroll
        for (int k = 0; k < 9; ++k) nw[k] = z2;
        #pragma unroll
        for (int i = 2; i <= 6; ++i) {
            float2 A, B, C; scoef(2, m + i - 4, A, B, C);
            nw[i-1] = cfma2(wv[i], A, nw[i-1]);
            nw[i]   = cfma2(wv[i], B, nw[i]);
            nw[i+1] = cfma2(wv[i], C, nw[i+1]);
        }
        #pragma unroll
        for (int k = 0; k < 9; ++k) wv[k] = nw[k];
        // apply U : width -> idx 0..8
        #pragma unroll
        for (int k = 0; k < 9; ++k) nw[k] = z2;
        #pragma unroll
        for (int i = 1; i <= 7; ++i) {
            float2 A, B, C; scoef(1, m + i - 4, A, B, C);
            nw[i-1] = cfma2(wv[i], A, nw[i-1]);
            nw[i]   = cfma2(wv[i], B, nw[i]);
            nw[i+1] = cfma2(wv[i], C, nw[i+1]);
        }
        #pragma unroll
        for (int k = 0; k < 9; ++k) cT[tid][k] = nw[k];
    }
    __syncthreads();

    for (int idx = tid; idx < 32*64; idx += 256) {
        int r = idx >> 6, d = idx & 63;
        float ox = 0.f, oy = 0.f;
        #pragma unroll
        for (int j = 0; j < 9; ++j) {
            float xv = xsr[(r + j)*64 + d];
            float2 t = cT[r][j];
            ox = fmaf(t.x, xv, ox);
            oy = fmaf(t.y, xv, oy);
        }
        unsigned long long ci = (unsigned long long)((bbase + n0 + r)*(size_t)cD + d0 + d);
        if (mode == 0) {
            if (ci < out_floats) outf[ci] = ox;
        } else {
            if (2ULL*ci + 2ULL <= out_floats) ((float2*)outf)[ci] = make_float2(ox, oy);
        }
    }
}

// ---------------------------------------------------------------------------
extern "C" void kernel_launch(void* const* d_in, const int* in_sizes, int n_in,
                              void* d_out, int out_size, void* d_ws, size_t ws_size,
                              hipStream_t stream)
{
    const int expect[12] = { cBN*cD, cD*cD, cD, 1, cD*cD, cD,
                             cD*cD, cD, 1, cD*cD, cD, cB*9 };
    bool ok = (n_in == 12);
    if (ok) for (int i = 0; i < 12; ++i) ok = ok && (in_sizes[i] == expect[i]);
    if (!ok) {
        sentinel_kernel<<<1, 1, 0, stream>>>((float*)d_out, out_size, 1.0e6f);
        return;
    }
    const size_t pBytes = (size_t)cB * 6 * cN * sizeof(float);       // 768 KB
    const size_t dBytes = (size_t)cBN * sizeof(float2);              // 256 KB
    const size_t wBytes = (size_t)8 * 65536 * sizeof(_Float16);      // 1 MB
    if (d_ws == nullptr || ws_size < pBytes + dBytes + wBytes) {
        sentinel_kernel<<<1, 1, 0, stream>>>((float*)d_out, out_size, 2.0e6f);
        return;
    }
    int mode;
    if (out_size == cBN * cD)          mode = 0;
    else if (out_size == 2 * cBN * cD) mode = 1;
    else {
        sentinel_kernel<<<1, 1, 0, stream>>>((float*)d_out, out_size, 3.0e6f);
        return;
    }

    const float* x     = (const float*)d_in[0];
    const float* ev_w1 = (const float*)d_in[1];
    const float* ev_b1 = (const float*)d_in[2];
    const float* ev_g  = (const float*)d_in[3];
    const float* ev_w2 = (const float*)d_in[4];
    const float* ev_b2 = (const float*)d_in[5];
    const float* hp_w1 = (const float*)d_in[6];
    const float* hp_b1 = (const float*)d_in[7];
    const float* hp_g  = (const float*)d_in[8];
    const float* hp_w2 = (const float*)d_in[9];
    const float* hp_b2 = (const float*)d_in[10];
    const float* cheb  = (const float*)d_in[11];

    float*     P    = (float*)d_ws;
    float2*    DIAG = (float2*)((char*)d_ws + pBytes);
    _Float16*  W16  = (_Float16*)((char*)d_ws + pBytes + dBytes);

    wcvt_kernel<<<dim3(256), 256, 0, stream>>>(ev_w1, ev_w2, hp_w1, hp_w2, W16);
    siren_mfma<<<dim3(cBN/64), 512, 0, stream>>>(x, W16, ev_b1, ev_g, ev_b2,
                                                 hp_b1, hp_g, hp_b2, cheb, P, DIAG);
    dhhp_stencil<<<dim3(cN/32, cD/64, cB), 256, 0, stream>>>(x, P, DIAG, (float*)d_out,
                                                             (unsigned long long)out_size,
                                                             mode);
}